// Round 1
// baseline (396.863 us; speedup 1.0000x reference)
//
#include <hip/hip_runtime.h>
#include <hip/hip_bf16.h>

typedef __attribute__((ext_vector_type(8))) short bf16x8;
typedef __attribute__((ext_vector_type(4))) float f32x4;

// round-to-nearest-even float -> bf16 bits
static __device__ __forceinline__ short f2bf(float x) {
    union { float f; unsigned u; } v; v.f = x;
    unsigned r = v.u + 0x7FFFu + ((v.u >> 16) & 1u);
    return (short)(r >> 16);
}

// W1 [K=256][N=256] fp32 -> W1T [N=256][K=256] bf16 (so B-frag reads are contiguous)
__global__ void prep_w1t(const float* __restrict__ W1, short* __restrict__ W1T) {
    int t = blockIdx.x * 256 + threadIdx.x;   // 0..65535
    int n = t >> 8, k = t & 255;
    W1T[t] = f2bf(W1[k * 256 + n]);
}

static __device__ __forceinline__ bf16x8 make_afrag(const float* __restrict__ p,
                                                    const float* __restrict__ q,
                                                    int kf) {
    float4 pa = *(const float4*)(p + kf);
    float4 pb = *(const float4*)(p + kf + 4);
    float4 qa = *(const float4*)(q + kf);
    float4 qb = *(const float4*)(q + kf + 4);
    float d0 = pa.x - qa.x, d1 = pa.y - qa.y, d2 = pa.z - qa.z, d3 = pa.w - qa.w;
    float d4 = pb.x - qb.x, d5 = pb.y - qb.y, d6 = pb.z - qb.z, d7 = pb.w - qb.w;
    bf16x8 a;
    a[0] = f2bf(d0 * d0); a[1] = f2bf(d1 * d1);
    a[2] = f2bf(d2 * d2); a[3] = f2bf(d3 * d3);
    a[4] = f2bf(d4 * d4); a[5] = f2bf(d5 * d5);
    a[6] = f2bf(d6 * d6); a[7] = f2bf(d7 * d7);
    return a;
}

// Block: 256 threads = 4 waves. BM = 128 rows (32 per wave, M-rep=2).
// Full N=256, K=256. A gathered from global (L3), B from L2-resident W1T.
__global__ __launch_bounds__(256, 2)
void pair_mlp(const int* __restrict__ pidx, const int* __restrict__ qidx,
              const float* __restrict__ emb, const short* __restrict__ w1t,
              const float* __restrict__ b1, const float* __restrict__ w2,
              const float* __restrict__ b2v_p, float* __restrict__ out, int M)
{
    const int tid  = threadIdx.x;
    const int lane = tid & 63;
    const int wv   = tid >> 6;          // wave 0..3
    const int c    = lane & 15;         // MFMA row/col select
    const int g    = lane >> 4;         // k-group 0..3
    const int rowBase = blockIdx.x * 128 + wv * 32;

    int m0 = rowBase + c;
    int m1 = rowBase + 16 + c;
    int mm0 = m0 < M ? m0 : M - 1;
    int mm1 = m1 < M ? m1 : M - 1;
    const float* p0 = emb + (size_t)pidx[mm0] * 256;
    const float* q0 = emb + (size_t)qidx[mm0] * 256;
    const float* p1 = emb + (size_t)pidx[mm1] * 256;
    const float* q1 = emb + (size_t)qidx[mm1] * 256;

    f32x4 acc[2][16];
#pragma unroll
    for (int r = 0; r < 2; ++r)
#pragma unroll
        for (int n = 0; n < 16; ++n) acc[r][n] = (f32x4)0.0f;

    const int koff = g * 8;                       // float offset within a K=32 chunk
    const short* bbase = w1t + c * 256 + g * 8;   // W1T[col][k] elements

    for (int kk = 0; kk < 8; ++kk) {
        const int kf = kk * 32 + koff;
        bf16x8 a0 = make_afrag(p0, q0, kf);
        bf16x8 a1 = make_afrag(p1, q1, kf);
#pragma unroll
        for (int n = 0; n < 16; ++n) {
            bf16x8 b = *(const bf16x8*)(bbase + n * 4096 + kk * 32);
            acc[0][n] = __builtin_amdgcn_mfma_f32_16x16x32_bf16(a0, b, acc[0][n], 0, 0, 0);
            acc[1][n] = __builtin_amdgcn_mfma_f32_16x16x32_bf16(a1, b, acc[1][n], 0, 0, 0);
        }
    }

    // Epilogue: h = relu(acc + b1); pred = h . W2 + b2
    float b2v = b2v_p[0];
    float part0[4] = {0.f, 0.f, 0.f, 0.f};
    float part1[4] = {0.f, 0.f, 0.f, 0.f};
#pragma unroll
    for (int n = 0; n < 16; ++n) {
        int cn = n * 16 + c;
        float b1v = b1[cn];
        float w2v = w2[cn];
#pragma unroll
        for (int j = 0; j < 4; ++j) {
            float h0 = acc[0][n][j] + b1v; h0 = h0 > 0.f ? h0 : 0.f;
            float h1 = acc[1][n][j] + b1v; h1 = h1 > 0.f ? h1 : 0.f;
            part0[j] += h0 * w2v;
            part1[j] += h1 * w2v;
        }
    }
    // reduce across the 16 lanes of each k-group-row set (lanes sharing g)
#pragma unroll
    for (int mk = 1; mk < 16; mk <<= 1) {
#pragma unroll
        for (int j = 0; j < 4; ++j) {
            part0[j] += __shfl_xor(part0[j], mk, 64);
            part1[j] += __shfl_xor(part1[j], mk, 64);
        }
    }

    if (c == 0) {
        int row0 = rowBase + g * 4;        // rep 0: rows g*4+j
        int row1 = rowBase + 16 + g * 4;   // rep 1
        float4 o0 = make_float4(part0[0] + b2v, part0[1] + b2v,
                                part0[2] + b2v, part0[3] + b2v);
        float4 o1 = make_float4(part1[0] + b2v, part1[1] + b2v,
                                part1[2] + b2v, part1[3] + b2v);
        if (row0 + 3 < M) *(float4*)(out + row0) = o0;
        else {
            if (row0 + 0 < M) out[row0 + 0] = o0.x;
            if (row0 + 1 < M) out[row0 + 1] = o0.y;
            if (row0 + 2 < M) out[row0 + 2] = o0.z;
            if (row0 + 3 < M) out[row0 + 3] = o0.w;
        }
        if (row1 + 3 < M) *(float4*)(out + row1) = o1;
        else {
            if (row1 + 0 < M) out[row1 + 0] = o1.x;
            if (row1 + 1 < M) out[row1 + 1] = o1.y;
            if (row1 + 2 < M) out[row1 + 2] = o1.z;
            if (row1 + 3 < M) out[row1 + 3] = o1.w;
        }
    }
}

extern "C" void kernel_launch(void* const* d_in, const int* in_sizes, int n_in,
                              void* d_out, int out_size, void* d_ws, size_t ws_size,
                              hipStream_t stream) {
    const int*   p   = (const int*)d_in[0];
    const int*   q   = (const int*)d_in[1];
    const float* emb = (const float*)d_in[2];
    const float* W1  = (const float*)d_in[3];
    const float* b1  = (const float*)d_in[4];
    const float* W2  = (const float*)d_in[5];
    const float* b2  = (const float*)d_in[6];
    float* out = (float*)d_out;
    short* w1t = (short*)d_ws;          // 256*256*2 = 128 KB scratch
    int M = in_sizes[0];

    prep_w1t<<<256, 256, 0, stream>>>(W1, w1t);
    int grid = (M + 127) / 128;
    pair_mlp<<<grid, 256, 0, stream>>>(p, q, emb, w1t, b1, W2, b2, out, M);
}

// Round 2
// 345.451 us; speedup vs baseline: 1.1488x; 1.1488x over previous
//
#include <hip/hip_runtime.h>
#include <hip/hip_bf16.h>

typedef __attribute__((ext_vector_type(8))) short bf16x8;
typedef __attribute__((ext_vector_type(4))) float f32x4;

// round-to-nearest-even float -> bf16 bits
static __device__ __forceinline__ short f2bf(float x) {
    union { float f; unsigned u; } v; v.f = x;
    unsigned r = v.u + 0x7FFFu + ((v.u >> 16) & 1u);
    return (short)(r >> 16);
}

// W1 [K=256][N=256] fp32 -> W1T [N=256][K=256] bf16 (contiguous B-frag reads)
__global__ void prep_w1t(const float* __restrict__ W1, short* __restrict__ W1T) {
    int t = blockIdx.x * 256 + threadIdx.x;   // 0..65535
    int n = t >> 8, k = t & 255;
    W1T[t] = f2bf(W1[k * 256 + n]);
}

// LDS row stride in shorts: 528 B = 33 * 16 B — consecutive rows shift one
// 16B bank-group, so ds_read_b128 of a k-slice across 16 rows spreads over
// all 8 bank-groups (pure-BW, no extra conflict). 512 B stride would alias.
#define LDSS 264

// Block: 256 threads = 4 waves, BM = 128 pairs (32 per wave, M-rep = 2).
// Phase 1: coalesced full-row gathers -> diff^2 bf16 tile in LDS.
// Phase 2: MFMA, A from LDS, B from L2-resident W1T.
__global__ __launch_bounds__(256, 2)
void pair_mlp(const int* __restrict__ pidx, const int* __restrict__ qidx,
              const float* __restrict__ emb, const short* __restrict__ w1t,
              const float* __restrict__ b1, const float* __restrict__ w2,
              const float* __restrict__ b2v_p, float* __restrict__ out, int M)
{
    __shared__ short At[128 * LDSS];   // 66 KB

    const int tid  = threadIdx.x;
    const int lane = tid & 63;
    const int wv   = tid >> 6;                // wave 0..3
    const int blockRow = blockIdx.x * 128;
    const int waveRow  = wv * 32;

    // ---- Phase 1: gather + (e_p - e_q)^2 -> bf16 -> LDS ----
    {
        int im = blockRow + waveRow + (lane & 31);
        im = im < M ? im : M - 1;
        int pi = pidx[im];                    // lanes 0..31 hold rows j=0..31
        int qi = qidx[im];
#pragma unroll 8
        for (int j = 0; j < 32; ++j) {
            int pr = __shfl(pi, j, 64);
            int qr = __shfl(qi, j, 64);
            const float4 pv = *(const float4*)(emb + (size_t)pr * 256 + lane * 4);
            const float4 qv = *(const float4*)(emb + (size_t)qr * 256 + lane * 4);
            float d0 = pv.x - qv.x, d1 = pv.y - qv.y;
            float d2 = pv.z - qv.z, d3 = pv.w - qv.w;
            short4 s;
            s.x = f2bf(d0 * d0); s.y = f2bf(d1 * d1);
            s.z = f2bf(d2 * d2); s.w = f2bf(d3 * d3);
            *(short4*)(At + (waveRow + j) * LDSS + lane * 4) = s;
        }
    }
    __syncthreads();

    // ---- Phase 2: [128 x 256] x [256 x 256] MFMA ----
    const int c = lane & 15;
    const int g = lane >> 4;

    f32x4 acc[2][16];
#pragma unroll
    for (int r = 0; r < 2; ++r)
#pragma unroll
        for (int n = 0; n < 16; ++n) acc[r][n] = (f32x4)0.0f;

    const short* bbase  = w1t + c * 256 + g * 8;
    const short* a0base = At + (waveRow + c) * LDSS + g * 8;
    const short* a1base = At + (waveRow + 16 + c) * LDSS + g * 8;

    for (int kk = 0; kk < 8; ++kk) {
        bf16x8 a0 = *(const bf16x8*)(a0base + kk * 32);
        bf16x8 a1 = *(const bf16x8*)(a1base + kk * 32);
#pragma unroll
        for (int n = 0; n < 16; ++n) {
            bf16x8 b = *(const bf16x8*)(bbase + n * 4096 + kk * 32);
            acc[0][n] = __builtin_amdgcn_mfma_f32_16x16x32_bf16(a0, b, acc[0][n], 0, 0, 0);
            acc[1][n] = __builtin_amdgcn_mfma_f32_16x16x32_bf16(a1, b, acc[1][n], 0, 0, 0);
        }
    }

    // ---- Epilogue: h = relu(acc + b1); pred = h . W2 + b2 ----
    float b2v = b2v_p[0];
    float part0[4] = {0.f, 0.f, 0.f, 0.f};
    float part1[4] = {0.f, 0.f, 0.f, 0.f};
#pragma unroll
    for (int n = 0; n < 16; ++n) {
        int cn = n * 16 + c;
        float b1v = b1[cn];
        float w2v = w2[cn];
#pragma unroll
        for (int j = 0; j < 4; ++j) {
            float h0 = acc[0][n][j] + b1v; h0 = h0 > 0.f ? h0 : 0.f;
            float h1 = acc[1][n][j] + b1v; h1 = h1 > 0.f ? h1 : 0.f;
            part0[j] += h0 * w2v;
            part1[j] += h1 * w2v;
        }
    }
#pragma unroll
    for (int mk = 1; mk < 16; mk <<= 1) {
#pragma unroll
        for (int j = 0; j < 4; ++j) {
            part0[j] += __shfl_xor(part0[j], mk, 64);
            part1[j] += __shfl_xor(part1[j], mk, 64);
        }
    }

    if (c == 0) {
        int row0 = blockRow + waveRow + g * 4;        // rep 0 rows
        int row1 = blockRow + waveRow + 16 + g * 4;   // rep 1 rows
        float4 o0 = make_float4(part0[0] + b2v, part0[1] + b2v,
                                part0[2] + b2v, part0[3] + b2v);
        float4 o1 = make_float4(part1[0] + b2v, part1[1] + b2v,
                                part1[2] + b2v, part1[3] + b2v);
        if (row0 + 3 < M) *(float4*)(out + row0) = o0;
        else {
            if (row0 + 0 < M) out[row0 + 0] = o0.x;
            if (row0 + 1 < M) out[row0 + 1] = o0.y;
            if (row0 + 2 < M) out[row0 + 2] = o0.z;
            if (row0 + 3 < M) out[row0 + 3] = o0.w;
        }
        if (row1 + 3 < M) *(float4*)(out + row1) = o1;
        else {
            if (row1 + 0 < M) out[row1 + 0] = o1.x;
            if (row1 + 1 < M) out[row1 + 1] = o1.y;
            if (row1 + 2 < M) out[row1 + 2] = o1.z;
            if (row1 + 3 < M) out[row1 + 3] = o1.w;
        }
    }
}

extern "C" void kernel_launch(void* const* d_in, const int* in_sizes, int n_in,
                              void* d_out, int out_size, void* d_ws, size_t ws_size,
                              hipStream_t stream) {
    const int*   p   = (const int*)d_in[0];
    const int*   q   = (const int*)d_in[1];
    const float* emb = (const float*)d_in[2];
    const float* W1  = (const float*)d_in[3];
    const float* b1  = (const float*)d_in[4];
    const float* W2  = (const float*)d_in[5];
    const float* b2  = (const float*)d_in[6];
    float* out = (float*)d_out;
    short* w1t = (short*)d_ws;          // 256*256*2 = 128 KB scratch
    int M = in_sizes[0];

    prep_w1t<<<256, 256, 0, stream>>>(W1, w1t);
    int grid = (M + 127) / 128;
    pair_mlp<<<grid, 256, 0, stream>>>(p, q, emb, w1t, b1, W2, b2, out, M);
}

// Round 3
// 214.512 us; speedup vs baseline: 1.8501x; 1.6104x over previous
//
#include <hip/hip_runtime.h>
#include <hip/hip_bf16.h>

typedef __attribute__((ext_vector_type(8))) short bf16x8;
typedef __attribute__((ext_vector_type(4))) float f32x4;

// round-to-nearest-even float -> bf16 bits
static __device__ __forceinline__ short f2bf(float x) {
    union { float f; unsigned u; } v; v.f = x;
    unsigned r = v.u + 0x7FFFu + ((v.u >> 16) & 1u);
    return (short)(r >> 16);
}

// W1 [K=256][N=256] fp32 -> W1T [N=256][K=256] bf16 (contiguous B-frag reads)
__global__ void prep_w1t(const float* __restrict__ W1, short* __restrict__ W1T) {
    int t = blockIdx.x * 256 + threadIdx.x;   // 0..65535
    int n = t >> 8, k = t & 255;
    W1T[t] = f2bf(W1[k * 256 + n]);
}

#define NBLK 256

// Persistent kernel. 512 threads = 8 waves. Tile BM=128 rows, full N=256, K=256.
// Wave w owns columns [w*32, w*32+32): its B slice lives in 64 VGPRs for the
// whole kernel. K-loop: 4 steps of K=64; A-slice [128][64] bf16 double-buffered
// in LDS with chunk^(row&7) XOR swizzle; gather loads for step s+1 issued
// before the MFMA phase of step s (latency hides under MFMA).
__global__ __launch_bounds__(512, 2)
void pair_mlp(const int* __restrict__ pidx, const int* __restrict__ qidx,
              const float* __restrict__ emb, const short* __restrict__ w1t,
              const float* __restrict__ b1, const float* __restrict__ w2,
              const float* __restrict__ b2p, float* __restrict__ out,
              int M, int NT)
{
    __shared__ short Abuf[2][128 * 64];   // 2 x 16 KB bf16 A-slices
    __shared__ float Red[8 * 128];        // 4 KB cross-wave reduction

    const int tid  = threadIdx.x;
    const int lane = tid & 63;
    const int wv   = tid >> 6;        // wave 0..7
    const int c    = lane & 15;       // MFMA row/col lane
    const int g    = lane >> 4;       // MFMA k-octet lane

    // ---- persistent per-wave B fragments: cols wv*32 + n*16 + c ----
    bf16x8 bfr[2][8];
#pragma unroll
    for (int n = 0; n < 2; ++n)
#pragma unroll
        for (int kc = 0; kc < 8; ++kc)
            bfr[n][kc] = *(const bf16x8*)(w1t + (wv * 32 + n * 16 + c) * 256 + kc * 32 + g * 8);

    float b1v[2], w2v[2];
#pragma unroll
    for (int n = 0; n < 2; ++n) {
        b1v[n] = b1[wv * 32 + n * 16 + c];
        w2v[n] = w2[wv * 32 + n * 16 + c];
    }
    const float b2v = b2p[0];

    const int r  = tid >> 2;          // row in tile 0..127 (gather/conv role)
    const int sg = tid & 3;           // 16-float segment 0..3

#define CONV_WRITE(BUF, PV0, PV1, PV2, PV3, QV0, QV1, QV2, QV3)                   \
    {                                                                              \
        bf16x8 A0, A1;                                                             \
        float d;                                                                   \
        d = PV0.x - QV0.x; A0[0] = f2bf(d * d);                                    \
        d = PV0.y - QV0.y; A0[1] = f2bf(d * d);                                    \
        d = PV0.z - QV0.z; A0[2] = f2bf(d * d);                                    \
        d = PV0.w - QV0.w; A0[3] = f2bf(d * d);                                    \
        d = PV1.x - QV1.x; A0[4] = f2bf(d * d);                                    \
        d = PV1.y - QV1.y; A0[5] = f2bf(d * d);                                    \
        d = PV1.z - QV1.z; A0[6] = f2bf(d * d);                                    \
        d = PV1.w - QV1.w; A0[7] = f2bf(d * d);                                    \
        d = PV2.x - QV2.x; A1[0] = f2bf(d * d);                                    \
        d = PV2.y - QV2.y; A1[1] = f2bf(d * d);                                    \
        d = PV2.z - QV2.z; A1[2] = f2bf(d * d);                                    \
        d = PV2.w - QV2.w; A1[3] = f2bf(d * d);                                    \
        d = PV3.x - QV3.x; A1[4] = f2bf(d * d);                                    \
        d = PV3.y - QV3.y; A1[5] = f2bf(d * d);                                    \
        d = PV3.z - QV3.z; A1[6] = f2bf(d * d);                                    \
        d = PV3.w - QV3.w; A1[7] = f2bf(d * d);                                    \
        short* wb = &Abuf[BUF][0];                                                 \
        int c0 = sg * 2, c1 = sg * 2 + 1;                                          \
        *(bf16x8*)(wb + r * 64 + ((c0 ^ (r & 7)) * 8)) = A0;                       \
        *(bf16x8*)(wb + r * 64 + ((c1 ^ (r & 7)) * 8)) = A1;                       \
    }

    for (int tile = blockIdx.x; tile < NT; tile += NBLK) {
        const int base = tile * 128;
        int im = base + r; im = im < M ? im : M - 1;
        const float* pp = emb + (size_t)pidx[im] * 256;
        const float* qp = emb + (size_t)qidx[im] * 256;

        f32x4 acc[8][2];
#pragma unroll
        for (int m = 0; m < 8; ++m) {
            acc[m][0] = (f32x4)0.0f;
            acc[m][1] = (f32x4)0.0f;
        }

        // ---- prologue: stage + conv step 0 into buf 0 ----
        {
            const float* ps = pp + sg * 16;
            const float* qs = qp + sg * 16;
            float4 pv0 = ((const float4*)ps)[0], pv1 = ((const float4*)ps)[1];
            float4 pv2 = ((const float4*)ps)[2], pv3 = ((const float4*)ps)[3];
            float4 qv0 = ((const float4*)qs)[0], qv1 = ((const float4*)qs)[1];
            float4 qv2 = ((const float4*)qs)[2], qv3 = ((const float4*)qs)[3];
            CONV_WRITE(0, pv0, pv1, pv2, pv3, qv0, qv1, qv2, qv3)
        }

#pragma unroll
        for (int s = 0; s < 4; ++s) {
            __syncthreads();   // conv(s) visible to all before MFMA(s)

            // issue gather loads for step s+1 (hide under MFMA phase)
            float4 pv0, pv1, pv2, pv3, qv0, qv1, qv2, qv3;
            if (s < 3) {
                const float* ps = pp + (s + 1) * 64 + sg * 16;
                const float* qs = qp + (s + 1) * 64 + sg * 16;
                pv0 = ((const float4*)ps)[0]; pv1 = ((const float4*)ps)[1];
                pv2 = ((const float4*)ps)[2]; pv3 = ((const float4*)ps)[3];
                qv0 = ((const float4*)qs)[0]; qv1 = ((const float4*)qs)[1];
                qv2 = ((const float4*)qs)[2]; qv3 = ((const float4*)qs)[3];
            }

            // ---- MFMA phase over Abuf[s&1] ----
            const short* ab = &Abuf[s & 1][0];
#pragma unroll
            for (int kk = 0; kk < 2; ++kk) {
#pragma unroll
                for (int m = 0; m < 8; ++m) {
                    bf16x8 a = *(const bf16x8*)(ab + (m * 16 + c) * 64 +
                                                (((kk * 4 + g) ^ (c & 7)) * 8));
                    acc[m][0] = __builtin_amdgcn_mfma_f32_16x16x32_bf16(
                        a, bfr[0][s * 2 + kk], acc[m][0], 0, 0, 0);
                    acc[m][1] = __builtin_amdgcn_mfma_f32_16x16x32_bf16(
                        a, bfr[1][s * 2 + kk], acc[m][1], 0, 0, 0);
                }
            }

            // ---- conv step s+1 into the other buffer ----
            if (s < 3) {
                CONV_WRITE((s + 1) & 1, pv0, pv1, pv2, pv3, qv0, qv1, qv2, qv3)
            }
        }

        // ---- epilogue: relu(acc+b1).w2, reduce over N ----
        float part[8][4];
#pragma unroll
        for (int m = 0; m < 8; ++m)
#pragma unroll
            for (int j = 0; j < 4; ++j) {
                float h0 = acc[m][0][j] + b1v[0]; h0 = h0 > 0.f ? h0 : 0.f;
                float h1 = acc[m][1][j] + b1v[1]; h1 = h1 > 0.f ? h1 : 0.f;
                part[m][j] = h0 * w2v[0] + h1 * w2v[1];
            }
#pragma unroll
        for (int mk = 1; mk < 16; mk <<= 1)
#pragma unroll
            for (int m = 0; m < 8; ++m)
#pragma unroll
                for (int j = 0; j < 4; ++j)
                    part[m][j] += __shfl_xor(part[m][j], mk, 64);

        if (c == 0) {
#pragma unroll
            for (int m = 0; m < 8; ++m) {
                float4 v = make_float4(part[m][0], part[m][1], part[m][2], part[m][3]);
                *(float4*)(&Red[wv * 128 + m * 16 + g * 4]) = v;
            }
        }
        __syncthreads();
        if (tid < 128) {
            int row = base + tid;
            if (row < M) {
                float sred = b2v;
#pragma unroll
                for (int w = 0; w < 8; ++w) sred += Red[w * 128 + tid];
                out[row] = sred;
            }
        }
        // next tile's first __syncthreads orders Red reuse
    }
#undef CONV_WRITE
}

extern "C" void kernel_launch(void* const* d_in, const int* in_sizes, int n_in,
                              void* d_out, int out_size, void* d_ws, size_t ws_size,
                              hipStream_t stream) {
    const int*   p   = (const int*)d_in[0];
    const int*   q   = (const int*)d_in[1];
    const float* emb = (const float*)d_in[2];
    const float* W1  = (const float*)d_in[3];
    const float* b1  = (const float*)d_in[4];
    const float* W2  = (const float*)d_in[5];
    const float* b2  = (const float*)d_in[6];
    float* out = (float*)d_out;
    short* w1t = (short*)d_ws;          // 256*256*2 = 128 KB scratch
    int M = in_sizes[0];
    int NT = (M + 127) / 128;

    prep_w1t<<<256, 256, 0, stream>>>(W1, w1t);
    pair_mlp<<<NBLK, 512, 0, stream>>>(p, q, emb, w1t, b1, W2, b2, out, M, NT);
}